// Round 8
// baseline (216.910 us; speedup 1.0000x reference)
//
#include <hip/hip_runtime.h>

typedef _Float16 f16;
typedef _Float16 f16x2 __attribute__((ext_vector_type(2)));
typedef _Float16 f16x4 __attribute__((ext_vector_type(4)));
typedef _Float16 f16x8 __attribute__((ext_vector_type(8)));
typedef float f32x4 __attribute__((ext_vector_type(4)));
typedef float f32x16 __attribute__((ext_vector_type(16)));

#define MFMA_F16(a, b, c) __builtin_amdgcn_mfma_f32_16x16x32_f16(a, b, c, 0, 0, 0)
#define MFMA32_F16(a, b, c) __builtin_amdgcn_mfma_f32_32x32x16_f16(a, b, c, 0, 0, 0)
// async global->LDS, 16B/lane. LDS dest is wave-uniform base + lane*16 (m104/m108).
#define ASYNC16(g, l) __builtin_amdgcn_global_load_lds(                              \
    (const __attribute__((address_space(1))) void*)(g),                              \
    (__attribute__((address_space(3))) void*)(l), 16, 0, 0)

// ---------------------------------------------------------------------------
// Kernel 1: fused pre-pass.  Blocks 0..4095: LayerNorm+cast of one token row.
// Blocks 4096..5375: weight cast/transpose tiles.
// wq scaled by 0.125*log2(e) (softmax scale + exp->exp2 fold).
// ---------------------------------------------------------------------------
__global__ __launch_bounds__(256)
void pre_kernel(const float* __restrict__ x, const float* __restrict__ gamma,
                const float* __restrict__ beta, f16* __restrict__ xn,
                const float* __restrict__ wq, const float* __restrict__ wk,
                const float* __restrict__ wv, const float* __restrict__ wo,
                const float* __restrict__ wout,
                f16* __restrict__ wqt, f16* __restrict__ wkt, f16* __restrict__ wvt,
                f16* __restrict__ wo_h, f16* __restrict__ woutt)
{
    const int t = threadIdx.x;
    if (blockIdx.x < 4096) {
        const int row = blockIdx.x;
        const float* xr = x + (size_t)row * 1024;
        float4 v = *(const float4*)(xr + t * 4);
        float s  = v.x + v.y + v.z + v.w;
        float ss = v.x * v.x + v.y * v.y + v.z * v.z + v.w * v.w;
#pragma unroll
        for (int off = 32; off > 0; off >>= 1) {
            s  += __shfl_down(s, off);
            ss += __shfl_down(ss, off);
        }
        __shared__ float wsum[4], wsq[4];
        const int wid = t >> 6, lane = t & 63;
        if (lane == 0) { wsum[wid] = s; wsq[wid] = ss; }
        __syncthreads();
        const float fs  = wsum[0] + wsum[1] + wsum[2] + wsum[3];
        const float fss = wsq[0] + wsq[1] + wsq[2] + wsq[3];
        const float mu  = fs * (1.0f / 1024.0f);
        const float var = fss * (1.0f / 1024.0f) - mu * mu;
        const float rs  = rsqrtf(var + 1e-5f);
        float4 g = *(const float4*)(gamma + t * 4);
        float4 b = *(const float4*)(beta + t * 4);
        f16x4 o;
        o[0] = (f16)((v.x - mu) * rs * g.x + b.x);
        o[1] = (f16)((v.y - mu) * rs * g.y + b.y);
        o[2] = (f16)((v.z - mu) * rs * g.z + b.z);
        o[3] = (f16)((v.w - mu) * rs * g.w + b.w);
        *(f16x4*)(xn + (size_t)row * 1024 + t * 4) = o;
        return;
    }
    const int pb = blockIdx.x - 4096;
    const int z = pb >> 8, rem = pb & 255;
    const int bx = rem & 15, by = rem >> 4;
    const float* src; f16* dst; int tr; float scl = 1.0f;
    switch (z) {
        case 0:  src = wq;   dst = wqt;   tr = 1; scl = 0.18033688011f; break;
        case 1:  src = wk;   dst = wkt;   tr = 1; break;
        case 2:  src = wv;   dst = wvt;   tr = 1; break;
        case 3:  src = wo;   dst = wo_h;  tr = 0; break;
        default: src = wout; dst = woutt; tr = 1; break;
    }
    const int r0 = by * 64, c0 = bx * 64;
    if (!tr) {
#pragma unroll
        for (int i = 0; i < 16; i++) {
            int idx = t + 256 * i;
            int r = idx >> 6, c = idx & 63;
            dst[(size_t)(r0 + r) * 1024 + c0 + c] = (f16)src[(size_t)(r0 + r) * 1024 + c0 + c];
        }
    } else {
        __shared__ __align__(16) f16 T[64][72];
#pragma unroll
        for (int i = 0; i < 16; i++) {
            int idx = t + 256 * i;
            int r = idx >> 6, c = idx & 63;
            T[r][c] = (f16)(src[(size_t)(r0 + r) * 1024 + c0 + c] * scl);
        }
        __syncthreads();
#pragma unroll
        for (int i = 0; i < 16; i++) {
            int idx = t + 256 * i;
            int r = idx >> 6, c = idx & 63;
            dst[(size_t)(c0 + r) * 1024 + r0 + c] = T[c][r];
        }
    }
}

// ---------------------------------------------------------------------------
// Kernel 2: merged QKV + W2 GEMM.  128x128 tile, BK=64, global_load_lds with
// XOR chunk swizzle.  Grid (32, 26): y<24 -> QKV; y>=24 -> 64 blocks of
// W2t = (wo@w_out)^T.  K = 1024 for both; branch is wave-uniform.
// ---------------------------------------------------------------------------
__global__ __launch_bounds__(256, 3)
void gemm_qkv_w2(const f16* __restrict__ A, const f16* __restrict__ Bt,
                 f16* __restrict__ Qd, f16* __restrict__ Kd, f16* __restrict__ Vd,
                 const f16* __restrict__ A2, const f16* __restrict__ Bt2,
                 f16* __restrict__ W2t)
{
    __shared__ __align__(16) f16 smem[2 * 128 * 64];   // As | Bs; reused as Cs
    f16* As = smem;
    f16* Bs = smem + 128 * 64;
    const int tid = threadIdx.x;
    const int wid = tid >> 6, lane = tid & 63;
    const int qq = lane >> 4, ml = lane & 15;
    const int row0 = (wid >> 1) * 64, col0 = (wid & 1) * 64;

    int mode, bx, by;
    const f16 *Abase, *Bbase;
    if (blockIdx.y < 24) {
        mode = 0; bx = blockIdx.x; by = blockIdx.y; Abase = A; Bbase = Bt;
    } else {
        mode = 1;
        int id = (blockIdx.y - 24) * 32 + blockIdx.x;   // 0..63
        bx = id & 7; by = id >> 3; Abase = A2; Bbase = Bt2;
    }
    const f16* Ab = Abase + (size_t)bx * 128 * 1024;
    const f16* Bb = Bbase + (size_t)by * 128 * 1024;
    const int sr = lane >> 3;                 // staging row within inst
    const int sc = ((lane & 7) ^ sr) * 8;     // swizzled global fetch chunk
    const int swz = ml & 7;                   // read-side row swizzle key

    f32x4 acc[4][4];
#pragma unroll
    for (int i = 0; i < 4; i++)
#pragma unroll
        for (int j = 0; j < 4; j++) acc[i][j] = (f32x4){0.f, 0.f, 0.f, 0.f};

    for (int k0 = 0; k0 < 1024; k0 += 64) {
        __syncthreads();
#pragma unroll
        for (int j = 0; j < 4; j++) {
            const int inst = wid * 4 + j;
            const int r = inst * 8 + sr;
            ASYNC16(Ab + (size_t)r * 1024 + k0 + sc, &As[inst * 512]);
            ASYNC16(Bb + (size_t)r * 1024 + k0 + sc, &Bs[inst * 512]);
        }
        __syncthreads();
#pragma unroll
        for (int kh = 0; kh < 2; kh++) {
            f16x8 af[4], bf[4];
#pragma unroll
            for (int mb = 0; mb < 4; mb++)
                af[mb] = *(const f16x8*)(&As[(row0 + mb * 16 + ml) * 64 + ((kh * 4 + qq) ^ swz) * 8]);
#pragma unroll
            for (int nb = 0; nb < 4; nb++)
                bf[nb] = *(const f16x8*)(&Bs[(col0 + nb * 16 + ml) * 64 + ((kh * 4 + qq) ^ swz) * 8]);
#pragma unroll
            for (int mb = 0; mb < 4; mb++)
#pragma unroll
                for (int nb = 0; nb < 4; nb++)
                    acc[mb][nb] = MFMA_F16(af[mb], bf[nb], acc[mb][nb]);
        }
    }

    // C-frag layout: col = lane&15, row = (lane>>4)*4 + reg   [m89]
    if (mode == 1) {
        const int rT = bx * 128 + row0 + qq * 4;
#pragma unroll
        for (int mb = 0; mb < 4; mb++)
#pragma unroll
            for (int nb = 0; nb < 4; nb++) {
                int c = by * 128 + col0 + nb * 16 + ml;
#pragma unroll
                for (int rg = 0; rg < 4; rg++)
                    W2t[(size_t)(rT + mb * 16 + rg) * 1024 + c] = (f16)acc[mb][nb][rg];
            }
        return;
    }
    // QKV: through-LDS transpose then coalesced stores
    __syncthreads();                      // all frag reads of smem done
    f16* Cs = smem;                       // 128 x 128 f16 = 32 KB
    const int sel = (by * 128) >> 10;     // 0=Q 1=K 2=V
    const int bb  = (bx * 128) >> 11;
    const int nl0 = (bx * 128) & 2047;
    const int h0  = (by & 7) * 2;
    if (sel < 2) {
#pragma unroll
        for (int mb = 0; mb < 4; mb++)
#pragma unroll
            for (int nb = 0; nb < 4; nb++) {
                int col = col0 + nb * 16 + ml;
#pragma unroll
                for (int rg = 0; rg < 4; rg++) {
                    int row = row0 + mb * 16 + qq * 4 + rg;
                    int ch = (col >> 3) ^ (row & 15);
                    Cs[row * 128 + ch * 8 + (col & 7)] = (f16)acc[mb][nb][rg];
                }
            }
        __syncthreads();
        f16* Dst = (sel == 0 ? Qd : Kd);
#pragma unroll
        for (int i = 0; i < 8; i++) {
            int idx = i * 256 + tid;
            int r = idx >> 4, ch = idx & 15;
            f16x8 v = *(const f16x8*)(&Cs[r * 128 + ((ch ^ (r & 15)) * 8)]);
            int hh = h0 + (ch >> 3), d0 = (ch & 7) * 8;
            *(f16x8*)(Dst + ((size_t)(bb * 16 + hh) * 2048 + nl0 + r) * 64 + d0) = v;
        }
    } else {
#pragma unroll
        for (int mb = 0; mb < 4; mb++)
#pragma unroll
            for (int nb = 0; nb < 4; nb++) {
                int col = col0 + nb * 16 + ml;
                int rch = ((row0 + mb * 16) >> 3) + (qq >> 1);
                int ch = rch ^ (col & 15);
                f16x4 w;
                w[0] = (f16)acc[mb][nb][0]; w[1] = (f16)acc[mb][nb][1];
                w[2] = (f16)acc[mb][nb][2]; w[3] = (f16)acc[mb][nb][3];
                *(f16x4*)(&Cs[col * 128 + ch * 8 + (qq & 1) * 4]) = w;
            }
        __syncthreads();
#pragma unroll
        for (int i = 0; i < 8; i++) {
            int idx = i * 256 + tid;
            int c = idx >> 4, tc = idx & 15;
            f16x8 v = *(const f16x8*)(&Cs[c * 128 + ((tc ^ (c & 15)) * 8)]);
            int hh = h0 + (c >> 6), d = c & 63;
            *(f16x8*)(Vd + ((size_t)(bb * 16 + hh) * 64 + d) * 2048 + nl0 + tc * 8) = v;
        }
    }
}

// ---------------------------------------------------------------------------
// Kernel 3: flash attention on 32x32x16 MFMA.  Block = 128 THREADS (2 waves),
// 64 q (wave = 32 q); grid 32x32 = 1024 blocks -> 5 blocks/CU, 10 waves/CU.
// BN=64 key tiles, double-buffered K/V staging (1 barrier/tile).  No P LDS
// round-trip (lane^32 shfl exchange).  S^T = K.Q^T; PV as D[d][q] = Vt.P.
// No-max softmax, P = exp2(S), scale folded into wq.  LDS = 32 KB.
// ---------------------------------------------------------------------------
__global__ __launch_bounds__(128, 4)
void flash_kernel(const f16* __restrict__ Q, const f16* __restrict__ K,
                  const f16* __restrict__ Vt, f16* __restrict__ O)
{
    __shared__ __align__(16) f16 Ks[2][64 * 64];    // [key][d]  chunk-swizzled
    __shared__ __align__(16) f16 Vts[2][64 * 64];   // [d][key]  chunk-swizzled

    const int bh = blockIdx.y;
    const int q0 = blockIdx.x * 64;
    const int tid = threadIdx.x, wid = tid >> 6, lane = tid & 63;
    const int ql = lane & 31;          // q (and K-row / V-row) index
    const int h  = lane >> 5;          // half
    const int sw = ql & 7;             // read-side swizzle key

    const f16* Qb = Q + ((size_t)bh * 2048 + q0 + wid * 32) * 64;
    const f16* Kb = K + (size_t)bh * 2048 * 64;
    const f16* Vb = Vt + (size_t)bh * 64 * 2048;

    // Q B-frags: qf[kt][j] = Q[q=ql][d = kt*16 + h*8 + j]
    f16x8 qf[4];
#pragma unroll
    for (int kt = 0; kt < 4; kt++)
        qf[kt] = *(const f16x8*)(Qb + (size_t)ql * 64 + kt * 16 + h * 8);

    f32x16 oacc[2];
#pragma unroll
    for (int db = 0; db < 2; db++)
#pragma unroll
        for (int r = 0; r < 16; r++) oacc[db][r] = 0.f;
    float lsum = 0.f;

    const int sr = lane >> 3, scw = ((lane & 7) ^ sr) * 8;   // staging swizzle

    // prologue: stage tile 0 into buffer 0 (8 K-insts + 8 V-insts over 2 waves)
#pragma unroll
    for (int j = 0; j < 4; j++) {
        const int inst = wid * 4 + j;
        const int r = inst * 8 + sr;
        ASYNC16(Kb + (size_t)r * 64 + scw, &Ks[0][inst * 512]);
        ASYNC16(Vb + (size_t)r * 2048 + scw, &Vts[0][inst * 512]);
    }
    __syncthreads();

    for (int t = 0; t < 32; t++) {
        const int buf = t & 1;
        if (t < 31) {
            const int t1 = (t + 1) * 64;
#pragma unroll
            for (int j = 0; j < 4; j++) {
                const int inst = wid * 4 + j;
                const int r = inst * 8 + sr;
                ASYNC16(Kb + ((size_t)t1 + r) * 64 + scw, &Ks[buf ^ 1][inst * 512]);
                ASYNC16(Vb + (size_t)r * 2048 + t1 + scw, &Vts[buf ^ 1][inst * 512]);
            }
        }

        // S^T: D[key][q], 2 key-blocks.  A = K-frag [m=key][k=d], B = qf.
        f32x16 s0, s1;
#pragma unroll
        for (int r = 0; r < 16; r++) { s0[r] = 0.f; s1[r] = 0.f; }
#pragma unroll
        for (int kt = 0; kt < 4; kt++) {
            const int ch = ((kt * 2 + h) ^ sw) * 8;
            f16x8 kf0 = *(const f16x8*)(&Ks[buf][ql * 64 + ch]);
            f16x8 kf1 = *(const f16x8*)(&Ks[buf][(32 + ql) * 64 + ch]);
            s0 = MFMA32_F16(kf0, qf[kt], s0);
            s1 = MFMA32_F16(kf1, qf[kt], s1);
        }

        // P = exp2(S); pack key-pairs; lane q=ql keeps its row sum.
        f16x2 pk[2][8], xp[2][8];
#pragma unroll
        for (int i = 0; i < 8; i++) {
            float a0 = __builtin_amdgcn_exp2f(s0[2 * i]);
            float a1 = __builtin_amdgcn_exp2f(s0[2 * i + 1]);
            float b0 = __builtin_amdgcn_exp2f(s1[2 * i]);
            float b1 = __builtin_amdgcn_exp2f(s1[2 * i + 1]);
            lsum += (a0 + a1) + (b0 + b1);
            pk[0][i] = __builtin_bit_cast(f16x2, __builtin_amdgcn_cvt_pkrtz(a0, a1));
            pk[1][i] = __builtin_bit_cast(f16x2, __builtin_amdgcn_cvt_pkrtz(b0, b1));
        }
        // cross-half exchange (lane ^ 32)
#pragma unroll
        for (int kb = 0; kb < 2; kb++)
#pragma unroll
            for (int i = 0; i < 8; i++)
                xp[kb][i] = __builtin_bit_cast(f16x2,
                    __shfl_xor(__builtin_bit_cast(int, pk[kb][i]), 32));

        // PV: D[d][q] += Vt-frag . P-frag
#pragma unroll
        for (int kt = 0; kt < 4; kt++) {
            const int kb = kt >> 1, c = (kt & 1) * 4;
            f16x2 b0 = h ? xp[kb][c + 2] : pk[kb][c];
            f16x2 b1 = h ? xp[kb][c + 3] : pk[kb][c + 1];
            f16x2 b2 = h ? pk[kb][c + 2] : xp[kb][c];
            f16x2 b3 = h ? pk[kb][c + 3] : xp[kb][c + 1];
            f16x8 pb;
            pb[0] = b0[0]; pb[1] = b0[1]; pb[2] = b1[0]; pb[3] = b1[1];
            pb[4] = b2[0]; pb[5] = b2[1]; pb[6] = b3[0]; pb[7] = b3[1];
            const int ch = ((kt * 2 + h) ^ sw) * 8;
            f16x8 vf0 = *(const f16x8*)(&Vts[buf][ql * 64 + ch]);
            f16x8 vf1 = *(const f16x8*)(&Vts[buf][(32 + ql) * 64 + ch]);
            oacc[0] = MFMA32_F16(vf0, pb, oacc[0]);
            oacc[1] = MFMA32_F16(vf1, pb, oacc[1]);
        }
        __syncthreads();   // drains prefetch + buffer swap
    }

    // total row sum for q = ql (halves hold complementary key sets)
    lsum += __builtin_bit_cast(float, __shfl_xor(__builtin_bit_cast(int, lsum), 32));
    const float linv = 1.0f / lsum;

    // D[d][q]: col = q = ql, row d = (reg&3) + 8*(reg>>2) + 4h (+32*db)
    const int bb = bh >> 4, hh = bh & 15;
    const int tok = q0 + wid * 32 + ql;
    f16* Ob = O + ((size_t)(bb * 2048 + tok)) * 1024 + hh * 64 + 4 * h;
#pragma unroll
    for (int db = 0; db < 2; db++)
#pragma unroll
        for (int m = 0; m < 4; m++) {
            f16x2 lo = __builtin_bit_cast(f16x2, __builtin_amdgcn_cvt_pkrtz(
                oacc[db][4 * m] * linv, oacc[db][4 * m + 1] * linv));
            f16x2 hi = __builtin_bit_cast(f16x2, __builtin_amdgcn_cvt_pkrtz(
                oacc[db][4 * m + 2] * linv, oacc[db][4 * m + 3] * linv));
            f16x4 w; w[0] = lo[0]; w[1] = lo[1]; w[2] = hi[0]; w[3] = hi[1];
            *(f16x4*)(Ob + db * 32 + m * 8) = w;
        }
}

// ---------------------------------------------------------------------------
// Kernel 4: final GEMM out = O[4096,1024] . W2t[1024,1024]^T + bias, fp32 out.
// 64x64 tiles -> grid (64,16) = 1024 blocks = 4 blocks/CU (16 waves/CU).
// 4 waves as 2x2 of 32x32.  LDS 16 KB.
// ---------------------------------------------------------------------------
__global__ __launch_bounds__(256, 4)
void gemm_final(const f16* __restrict__ A, const f16* __restrict__ Bt,
                float* __restrict__ C, const float* __restrict__ bias)
{
    __shared__ __align__(16) f16 As[64 * 64];
    __shared__ __align__(16) f16 Bs[64 * 64];
    const int tid = threadIdx.x;
    const int wid = tid >> 6, lane = tid & 63;
    const int qq = lane >> 4, ml = lane & 15;
    const int row0 = (wid >> 1) * 32, col0 = (wid & 1) * 32;
    const f16* Ab = A + (size_t)blockIdx.x * 64 * 1024;
    const f16* Bb = Bt + (size_t)blockIdx.y * 64 * 1024;
    const int sr = lane >> 3;
    const int sc = ((lane & 7) ^ sr) * 8;
    const int swz = ml & 7;

    f32x4 acc[2][2];
#pragma unroll
    for (int i = 0; i < 2; i++)
#pragma unroll
        for (int j = 0; j < 2; j++) acc[i][j] = (f32x4){0.f, 0.f, 0.f, 0.f};

    for (int k0 = 0; k0 < 1024; k0 += 64) {
        __syncthreads();
#pragma unroll
        for (int j = 0; j < 2; j++) {
            const int inst = wid * 2 + j;
            const int r = inst * 8 + sr;
            ASYNC16(Ab + (size_t)r * 1024 + k0 + sc, &As[inst * 512]);
            ASYNC16(Bb + (size_t)r * 1024 + k0 + sc, &Bs[inst * 512]);
        }
        __syncthreads();
#pragma unroll
        for (int kh = 0; kh < 2; kh++) {
            f16x8 af[2], bf[2];
#pragma unroll
            for (int mb = 0; mb < 2; mb++)
                af[mb] = *(const f16x8*)(&As[(row0 + mb * 16 + ml) * 64 + ((kh * 4 + qq) ^ swz) * 8]);
#pragma unroll
            for (int nb = 0; nb < 2; nb++)
                bf[nb] = *(const f16x8*)(&Bs[(col0 + nb * 16 + ml) * 64 + ((kh * 4 + qq) ^ swz) * 8]);
#pragma unroll
            for (int mb = 0; mb < 2; mb++)
#pragma unroll
                for (int nb = 0; nb < 2; nb++)
                    acc[mb][nb] = MFMA_F16(af[mb], bf[nb], acc[mb][nb]);
        }
    }

    const int rT = blockIdx.x * 64 + row0 + qq * 4;
#pragma unroll
    for (int mb = 0; mb < 2; mb++)
#pragma unroll
        for (int nb = 0; nb < 2; nb++) {
            int c = blockIdx.y * 64 + col0 + nb * 16 + ml;
            float bv = bias[c];
#pragma unroll
            for (int rg = 0; rg < 4; rg++)
                C[(size_t)(rT + mb * 16 + rg) * 1024 + c] = acc[mb][nb][rg] + bv;
        }
}

// ---------------------------------------------------------------------------
extern "C" void kernel_launch(void* const* d_in, const int* in_sizes, int n_in,
                              void* d_out, int out_size, void* d_ws, size_t ws_size,
                              hipStream_t stream)
{
    const float* x     = (const float*)d_in[0];
    const float* gamma = (const float*)d_in[1];
    const float* beta  = (const float*)d_in[2];
    const float* wq    = (const float*)d_in[3];
    const float* wk    = (const float*)d_in[4];
    const float* wv    = (const float*)d_in[5];
    const float* wo    = (const float*)d_in[6];
    const float* wout  = (const float*)d_in[7];
    const float* bout  = (const float*)d_in[8];
    float* out = (float*)d_out;

    char* ws = (char*)d_ws;
    const size_t MB = 1 << 20;
    f16* xn    = (f16*)(ws + 0);        // 8 MB [4096][1024]; reused as O after QKV
    f16* wqt   = (f16*)(ws + 8 * MB);   // wqt/wkt/wvt contiguous = [3072][1024]
    f16* wkt   = (f16*)(ws + 10 * MB);
    f16* wvt   = (f16*)(ws + 12 * MB);
    f16* wo_h  = (f16*)(ws + 14 * MB);
    f16* woutt = (f16*)(ws + 16 * MB);
    f16* W2t   = (f16*)(ws + 18 * MB);  // (wo @ w_out)^T fp16
    f16* Qh    = (f16*)(ws + 20 * MB);  // 8 MB [32][2048][64]
    f16* Kh    = (f16*)(ws + 28 * MB);  // 8 MB [32][2048][64]
    f16* Vth   = (f16*)(ws + 36 * MB);  // 8 MB [32][64][2048]
    f16* Oh    = xn;                    // alias: xn dead after QKV GEMM

    pre_kernel<<<5376, 256, 0, stream>>>(x, gamma, beta, xn, wq, wk, wv, wo, wout,
                                         wqt, wkt, wvt, wo_h, woutt);
    // fused QKV (A[4096,1024] x Wqkv_t[3072,1024]^T) + W2t (64 tail blocks)
    gemm_qkv_w2<<<dim3(32, 26), 256, 0, stream>>>(xn, wqt, Qh, Kh, Vth,
                                                  woutt, wo_h, W2t);
    flash_kernel<<<dim3(32, 32), 128, 0, stream>>>(Qh, Kh, Vth, Oh);
    gemm_final<<<dim3(64, 16), 256, 0, stream>>>(Oh, W2t, out, bout);
}

// Round 9
// 207.193 us; speedup vs baseline: 1.0469x; 1.0469x over previous
//
#include <hip/hip_runtime.h>

typedef _Float16 f16;
typedef _Float16 f16x2 __attribute__((ext_vector_type(2)));
typedef _Float16 f16x4 __attribute__((ext_vector_type(4)));
typedef _Float16 f16x8 __attribute__((ext_vector_type(8)));
typedef float f32x4 __attribute__((ext_vector_type(4)));
typedef float f32x16 __attribute__((ext_vector_type(16)));

#define MFMA_F16(a, b, c) __builtin_amdgcn_mfma_f32_16x16x32_f16(a, b, c, 0, 0, 0)
#define MFMA32_F16(a, b, c) __builtin_amdgcn_mfma_f32_32x32x16_f16(a, b, c, 0, 0, 0)
// async global->LDS, 16B/lane. LDS dest is wave-uniform base + lane*16 (m104/m108).
#define ASYNC16(g, l) __builtin_amdgcn_global_load_lds(                              \
    (const __attribute__((address_space(1))) void*)(g),                              \
    (__attribute__((address_space(3))) void*)(l), 16, 0, 0)

// ---------------------------------------------------------------------------
// Kernel 1: fused pre-pass.  Blocks 0..4095: LayerNorm+cast of one token row.
// Blocks 4096..5375: weight cast/transpose tiles.
// wq scaled by 0.125*log2(e) (softmax scale + exp->exp2 fold).
// ---------------------------------------------------------------------------
__global__ __launch_bounds__(256)
void pre_kernel(const float* __restrict__ x, const float* __restrict__ gamma,
                const float* __restrict__ beta, f16* __restrict__ xn,
                const float* __restrict__ wq, const float* __restrict__ wk,
                const float* __restrict__ wv, const float* __restrict__ wo,
                const float* __restrict__ wout,
                f16* __restrict__ wqt, f16* __restrict__ wkt, f16* __restrict__ wvt,
                f16* __restrict__ wo_h, f16* __restrict__ woutt)
{
    const int t = threadIdx.x;
    if (blockIdx.x < 4096) {
        const int row = blockIdx.x;
        const float* xr = x + (size_t)row * 1024;
        float4 v = *(const float4*)(xr + t * 4);
        float s  = v.x + v.y + v.z + v.w;
        float ss = v.x * v.x + v.y * v.y + v.z * v.z + v.w * v.w;
#pragma unroll
        for (int off = 32; off > 0; off >>= 1) {
            s  += __shfl_down(s, off);
            ss += __shfl_down(ss, off);
        }
        __shared__ float wsum[4], wsq[4];
        const int wid = t >> 6, lane = t & 63;
        if (lane == 0) { wsum[wid] = s; wsq[wid] = ss; }
        __syncthreads();
        const float fs  = wsum[0] + wsum[1] + wsum[2] + wsum[3];
        const float fss = wsq[0] + wsq[1] + wsq[2] + wsq[3];
        const float mu  = fs * (1.0f / 1024.0f);
        const float var = fss * (1.0f / 1024.0f) - mu * mu;
        const float rs  = rsqrtf(var + 1e-5f);
        float4 g = *(const float4*)(gamma + t * 4);
        float4 b = *(const float4*)(beta + t * 4);
        f16x4 o;
        o[0] = (f16)((v.x - mu) * rs * g.x + b.x);
        o[1] = (f16)((v.y - mu) * rs * g.y + b.y);
        o[2] = (f16)((v.z - mu) * rs * g.z + b.z);
        o[3] = (f16)((v.w - mu) * rs * g.w + b.w);
        *(f16x4*)(xn + (size_t)row * 1024 + t * 4) = o;
        return;
    }
    const int pb = blockIdx.x - 4096;
    const int z = pb >> 8, rem = pb & 255;
    const int bx = rem & 15, by = rem >> 4;
    const float* src; f16* dst; int tr; float scl = 1.0f;
    switch (z) {
        case 0:  src = wq;   dst = wqt;   tr = 1; scl = 0.18033688011f; break;
        case 1:  src = wk;   dst = wkt;   tr = 1; break;
        case 2:  src = wv;   dst = wvt;   tr = 1; break;
        case 3:  src = wo;   dst = wo_h;  tr = 0; break;
        default: src = wout; dst = woutt; tr = 1; break;
    }
    const int r0 = by * 64, c0 = bx * 64;
    if (!tr) {
#pragma unroll
        for (int i = 0; i < 16; i++) {
            int idx = t + 256 * i;
            int r = idx >> 6, c = idx & 63;
            dst[(size_t)(r0 + r) * 1024 + c0 + c] = (f16)src[(size_t)(r0 + r) * 1024 + c0 + c];
        }
    } else {
        __shared__ __align__(16) f16 T[64][72];
#pragma unroll
        for (int i = 0; i < 16; i++) {
            int idx = t + 256 * i;
            int r = idx >> 6, c = idx & 63;
            T[r][c] = (f16)(src[(size_t)(r0 + r) * 1024 + c0 + c] * scl);
        }
        __syncthreads();
#pragma unroll
        for (int i = 0; i < 16; i++) {
            int idx = t + 256 * i;
            int r = idx >> 6, c = idx & 63;
            dst[(size_t)(c0 + r) * 1024 + r0 + c] = T[c][r];
        }
    }
}

// ---------------------------------------------------------------------------
// Kernel 2: merged QKV + W2 GEMM.  128x128 tile, BK=64, global_load_lds with
// XOR chunk swizzle.  Grid (32, 26): y<24 -> QKV; y>=24 -> 64 blocks of
// W2t = (wo@w_out)^T.  K = 1024 for both; branch is wave-uniform.
// ---------------------------------------------------------------------------
__global__ __launch_bounds__(256, 3)
void gemm_qkv_w2(const f16* __restrict__ A, const f16* __restrict__ Bt,
                 f16* __restrict__ Qd, f16* __restrict__ Kd, f16* __restrict__ Vd,
                 const f16* __restrict__ A2, const f16* __restrict__ Bt2,
                 f16* __restrict__ W2t)
{
    __shared__ __align__(16) f16 smem[2 * 128 * 64];   // As | Bs; reused as Cs
    f16* As = smem;
    f16* Bs = smem + 128 * 64;
    const int tid = threadIdx.x;
    const int wid = tid >> 6, lane = tid & 63;
    const int qq = lane >> 4, ml = lane & 15;
    const int row0 = (wid >> 1) * 64, col0 = (wid & 1) * 64;

    int mode, bx, by;
    const f16 *Abase, *Bbase;
    if (blockIdx.y < 24) {
        mode = 0; bx = blockIdx.x; by = blockIdx.y; Abase = A; Bbase = Bt;
    } else {
        mode = 1;
        int id = (blockIdx.y - 24) * 32 + blockIdx.x;   // 0..63
        bx = id & 7; by = id >> 3; Abase = A2; Bbase = Bt2;
    }
    const f16* Ab = Abase + (size_t)bx * 128 * 1024;
    const f16* Bb = Bbase + (size_t)by * 128 * 1024;
    const int sr = lane >> 3;                 // staging row within inst
    const int sc = ((lane & 7) ^ sr) * 8;     // swizzled global fetch chunk
    const int swz = ml & 7;                   // read-side row swizzle key

    f32x4 acc[4][4];
#pragma unroll
    for (int i = 0; i < 4; i++)
#pragma unroll
        for (int j = 0; j < 4; j++) acc[i][j] = (f32x4){0.f, 0.f, 0.f, 0.f};

    for (int k0 = 0; k0 < 1024; k0 += 64) {
        __syncthreads();
#pragma unroll
        for (int j = 0; j < 4; j++) {
            const int inst = wid * 4 + j;
            const int r = inst * 8 + sr;
            ASYNC16(Ab + (size_t)r * 1024 + k0 + sc, &As[inst * 512]);
            ASYNC16(Bb + (size_t)r * 1024 + k0 + sc, &Bs[inst * 512]);
        }
        __syncthreads();
#pragma unroll
        for (int kh = 0; kh < 2; kh++) {
            f16x8 af[4], bf[4];
#pragma unroll
            for (int mb = 0; mb < 4; mb++)
                af[mb] = *(const f16x8*)(&As[(row0 + mb * 16 + ml) * 64 + ((kh * 4 + qq) ^ swz) * 8]);
#pragma unroll
            for (int nb = 0; nb < 4; nb++)
                bf[nb] = *(const f16x8*)(&Bs[(col0 + nb * 16 + ml) * 64 + ((kh * 4 + qq) ^ swz) * 8]);
#pragma unroll
            for (int mb = 0; mb < 4; mb++)
#pragma unroll
                for (int nb = 0; nb < 4; nb++)
                    acc[mb][nb] = MFMA_F16(af[mb], bf[nb], acc[mb][nb]);
        }
    }

    // C-frag layout: col = lane&15, row = (lane>>4)*4 + reg   [m89]
    if (mode == 1) {
        const int rT = bx * 128 + row0 + qq * 4;
#pragma unroll
        for (int mb = 0; mb < 4; mb++)
#pragma unroll
            for (int nb = 0; nb < 4; nb++) {
                int c = by * 128 + col0 + nb * 16 + ml;
#pragma unroll
                for (int rg = 0; rg < 4; rg++)
                    W2t[(size_t)(rT + mb * 16 + rg) * 1024 + c] = (f16)acc[mb][nb][rg];
            }
        return;
    }
    // QKV: through-LDS transpose then coalesced stores
    __syncthreads();                      // all frag reads of smem done
    f16* Cs = smem;                       // 128 x 128 f16 = 32 KB
    const int sel = (by * 128) >> 10;     // 0=Q 1=K 2=V
    const int bb  = (bx * 128) >> 11;
    const int nl0 = (bx * 128) & 2047;
    const int h0  = (by & 7) * 2;
    if (sel < 2) {
#pragma unroll
        for (int mb = 0; mb < 4; mb++)
#pragma unroll
            for (int nb = 0; nb < 4; nb++) {
                int col = col0 + nb * 16 + ml;
#pragma unroll
                for (int rg = 0; rg < 4; rg++) {
                    int row = row0 + mb * 16 + qq * 4 + rg;
                    int ch = (col >> 3) ^ (row & 15);
                    Cs[row * 128 + ch * 8 + (col & 7)] = (f16)acc[mb][nb][rg];
                }
            }
        __syncthreads();
        f16* Dst = (sel == 0 ? Qd : Kd);
#pragma unroll
        for (int i = 0; i < 8; i++) {
            int idx = i * 256 + tid;
            int r = idx >> 4, ch = idx & 15;
            f16x8 v = *(const f16x8*)(&Cs[r * 128 + ((ch ^ (r & 15)) * 8)]);
            int hh = h0 + (ch >> 3), d0 = (ch & 7) * 8;
            *(f16x8*)(Dst + ((size_t)(bb * 16 + hh) * 2048 + nl0 + r) * 64 + d0) = v;
        }
    } else {
#pragma unroll
        for (int mb = 0; mb < 4; mb++)
#pragma unroll
            for (int nb = 0; nb < 4; nb++) {
                int col = col0 + nb * 16 + ml;
                int rch = ((row0 + mb * 16) >> 3) + (qq >> 1);
                int ch = rch ^ (col & 15);
                f16x4 w;
                w[0] = (f16)acc[mb][nb][0]; w[1] = (f16)acc[mb][nb][1];
                w[2] = (f16)acc[mb][nb][2]; w[3] = (f16)acc[mb][nb][3];
                *(f16x4*)(&Cs[col * 128 + ch * 8 + (qq & 1) * 4]) = w;
            }
        __syncthreads();
#pragma unroll
        for (int i = 0; i < 8; i++) {
            int idx = i * 256 + tid;
            int c = idx >> 4, tc = idx & 15;
            f16x8 v = *(const f16x8*)(&Cs[c * 128 + ((tc ^ (c & 15)) * 8)]);
            int hh = h0 + (c >> 6), d = c & 63;
            *(f16x8*)(Vd + ((size_t)(bb * 16 + hh) * 64 + d) * 2048 + nl0 + tc * 8) = v;
        }
    }
}

// ---------------------------------------------------------------------------
// Kernel 3: SPLIT-K flash attention on 32x32x16 MFMA.  Grid (16, 32, 2):
// z = key-split (1024 keys each).  Block = 256 threads (4 waves x 32 q =
// 128 q).  4096 waves total = 16 waves/CU.  No-max softmax is ADDITIVE over
// key splits: each split writes unnormalized O-partial (f16) + l-partial;
// gemm_final combines.  BN=64 key tiles, double-buffered staging (1 barrier/
// tile), no P LDS round-trip (lane^32 shfl).  LDS = 32 KB.
// ---------------------------------------------------------------------------
__global__ __launch_bounds__(256, 2)
void flash_kernel(const f16* __restrict__ Q, const f16* __restrict__ K,
                  const f16* __restrict__ Vt, f16* __restrict__ Op0,
                  f16* __restrict__ Op1, float* __restrict__ lp)
{
    __shared__ __align__(16) f16 Ks[2][64 * 64];    // [key][d]  chunk-swizzled
    __shared__ __align__(16) f16 Vts[2][64 * 64];   // [d][key]  chunk-swizzled

    const int bh = blockIdx.y;
    const int q0 = blockIdx.x * 128;
    const int ks = blockIdx.z;          // key split 0/1
    const int tid = threadIdx.x, wid = tid >> 6, lane = tid & 63;
    const int ql = lane & 31;           // q (and K-row / V-row) index
    const int h  = lane >> 5;           // half
    const int sw = ql & 7;              // read-side swizzle key

    const f16* Qb = Q + ((size_t)bh * 2048 + q0 + wid * 32) * 64;
    const f16* Kb = K + (size_t)bh * 2048 * 64 + (size_t)ks * 1024 * 64;
    const f16* Vb = Vt + (size_t)bh * 64 * 2048 + ks * 1024;

    // Q B-frags: qf[kt][j] = Q[q=ql][d = kt*16 + h*8 + j]
    f16x8 qf[4];
#pragma unroll
    for (int kt = 0; kt < 4; kt++)
        qf[kt] = *(const f16x8*)(Qb + (size_t)ql * 64 + kt * 16 + h * 8);

    f32x16 oacc[2];
#pragma unroll
    for (int db = 0; db < 2; db++)
#pragma unroll
        for (int r = 0; r < 16; r++) oacc[db][r] = 0.f;
    float lsum = 0.f;

    const int sr = lane >> 3, scw = ((lane & 7) ^ sr) * 8;   // staging swizzle

    // prologue: stage tile 0 into buffer 0
#pragma unroll
    for (int j = 0; j < 2; j++) {
        const int inst = wid * 2 + j;
        const int r = inst * 8 + sr;
        ASYNC16(Kb + (size_t)r * 64 + scw, &Ks[0][inst * 512]);
        ASYNC16(Vb + (size_t)r * 2048 + scw, &Vts[0][inst * 512]);
    }
    __syncthreads();

    for (int t = 0; t < 16; t++) {
        const int buf = t & 1;
        if (t < 15) {
            const int t1 = (t + 1) * 64;
#pragma unroll
            for (int j = 0; j < 2; j++) {
                const int inst = wid * 2 + j;
                const int r = inst * 8 + sr;
                ASYNC16(Kb + ((size_t)t1 + r) * 64 + scw, &Ks[buf ^ 1][inst * 512]);
                ASYNC16(Vb + (size_t)r * 2048 + t1 + scw, &Vts[buf ^ 1][inst * 512]);
            }
        }

        // S^T: D[key][q], 2 key-blocks.  A = K-frag [m=key][k=d], B = qf.
        f32x16 s0, s1;
#pragma unroll
        for (int r = 0; r < 16; r++) { s0[r] = 0.f; s1[r] = 0.f; }
#pragma unroll
        for (int kt = 0; kt < 4; kt++) {
            const int ch = ((kt * 2 + h) ^ sw) * 8;
            f16x8 kf0 = *(const f16x8*)(&Ks[buf][ql * 64 + ch]);
            f16x8 kf1 = *(const f16x8*)(&Ks[buf][(32 + ql) * 64 + ch]);
            s0 = MFMA32_F16(kf0, qf[kt], s0);
            s1 = MFMA32_F16(kf1, qf[kt], s1);
        }

        // P = exp2(S); pack key-pairs; lane q=ql keeps its row sum.
        f16x2 pk[2][8], xp[2][8];
#pragma unroll
        for (int i = 0; i < 8; i++) {
            float a0 = __builtin_amdgcn_exp2f(s0[2 * i]);
            float a1 = __builtin_amdgcn_exp2f(s0[2 * i + 1]);
            float b0 = __builtin_amdgcn_exp2f(s1[2 * i]);
            float b1 = __builtin_amdgcn_exp2f(s1[2 * i + 1]);
            lsum += (a0 + a1) + (b0 + b1);
            pk[0][i] = __builtin_bit_cast(f16x2, __builtin_amdgcn_cvt_pkrtz(a0, a1));
            pk[1][i] = __builtin_bit_cast(f16x2, __builtin_amdgcn_cvt_pkrtz(b0, b1));
        }
        // cross-half exchange (lane ^ 32)
#pragma unroll
        for (int kb = 0; kb < 2; kb++)
#pragma unroll
            for (int i = 0; i < 8; i++)
                xp[kb][i] = __builtin_bit_cast(f16x2,
                    __shfl_xor(__builtin_bit_cast(int, pk[kb][i]), 32));

        // PV: D[d][q] += Vt-frag . P-frag
#pragma unroll
        for (int kt = 0; kt < 4; kt++) {
            const int kb = kt >> 1, c = (kt & 1) * 4;
            f16x2 b0 = h ? xp[kb][c + 2] : pk[kb][c];
            f16x2 b1 = h ? xp[kb][c + 3] : pk[kb][c + 1];
            f16x2 b2 = h ? pk[kb][c + 2] : xp[kb][c];
            f16x2 b3 = h ? pk[kb][c + 3] : xp[kb][c + 1];
            f16x8 pb;
            pb[0] = b0[0]; pb[1] = b0[1]; pb[2] = b1[0]; pb[3] = b1[1];
            pb[4] = b2[0]; pb[5] = b2[1]; pb[6] = b3[0]; pb[7] = b3[1];
            const int ch = ((kt * 2 + h) ^ sw) * 8;
            f16x8 vf0 = *(const f16x8*)(&Vts[buf][ql * 64 + ch]);
            f16x8 vf1 = *(const f16x8*)(&Vts[buf][(32 + ql) * 64 + ch]);
            oacc[0] = MFMA32_F16(vf0, pb, oacc[0]);
            oacc[1] = MFMA32_F16(vf1, pb, oacc[1]);
        }
        __syncthreads();   // drains prefetch + buffer swap
    }

    // split-local row sum for q = ql (halves hold complementary key sets)
    lsum += __builtin_bit_cast(float, __shfl_xor(__builtin_bit_cast(int, lsum), 32));

    const int bb = bh >> 4, hh = bh & 15;
    const int tok = q0 + wid * 32 + ql;
    if (h == 0) lp[(size_t)ks * 65536 + bh * 2048 + tok] = lsum;

    // UNNORMALIZED partial write.  D[d][q]: col = q = ql,
    // row d = (reg&3) + 8*(reg>>2) + 4h (+32*db)
    f16* Op = ks ? Op1 : Op0;
    f16* Ob = Op + ((size_t)(bb * 2048 + tok)) * 1024 + hh * 64 + 4 * h;
#pragma unroll
    for (int db = 0; db < 2; db++)
#pragma unroll
        for (int m = 0; m < 4; m++) {
            f16x2 lo = __builtin_bit_cast(f16x2, __builtin_amdgcn_cvt_pkrtz(
                oacc[db][4 * m], oacc[db][4 * m + 1]));
            f16x2 hi = __builtin_bit_cast(f16x2, __builtin_amdgcn_cvt_pkrtz(
                oacc[db][4 * m + 2], oacc[db][4 * m + 3]));
            f16x4 w; w[0] = lo[0]; w[1] = lo[1]; w[2] = hi[0]; w[3] = hi[1];
            *(f16x4*)(Ob + db * 32 + m * 8) = w;
        }
}

// ---------------------------------------------------------------------------
// Kernel 4: fused combine + final GEMM.
// out = (diag-scale((Op0+Op1), 1/(l0+l1)) @ W2t^T) + bias, fp32 out.
// BK=64 is head-aligned, so the softmax normalization scale is per-row
// uniform within each k-iteration: scale A-frags by linv[row][k0>>6].
// 64x64 tiles -> grid (64,16) = 1024 blocks = 4 blocks/CU.  LDS 26 KB.
// ---------------------------------------------------------------------------
__global__ __launch_bounds__(256, 4)
void gemm_final(const f16* __restrict__ A0, const f16* __restrict__ A1,
                const f16* __restrict__ Bt, const float* __restrict__ lp,
                float* __restrict__ C, const float* __restrict__ bias)
{
    __shared__ __align__(16) f16 As0[64 * 64];
    __shared__ __align__(16) f16 As1[64 * 64];
    __shared__ __align__(16) f16 Bs[64 * 64];
    __shared__ f16 lh[16][64];          // linv[head][row-local]
    const int tid = threadIdx.x;
    const int wid = tid >> 6, lane = tid & 63;
    const int qq = lane >> 4, ml = lane & 15;
    const int row0 = (wid >> 1) * 32, col0 = (wid & 1) * 32;
    const int r0g = blockIdx.x * 64;
    const f16* Ab0 = A0 + (size_t)r0g * 1024;
    const f16* Ab1 = A1 + (size_t)r0g * 1024;
    const f16* Bb = Bt + (size_t)blockIdx.y * 64 * 1024;
    const int sr = lane >> 3;
    const int sc = ((lane & 7) ^ sr) * 8;
    const int swz = ml & 7;

    // stage linv tile: 16 heads x 64 rows
    {
        const int bb = r0g >> 11, t0 = r0g & 2047;
#pragma unroll
        for (int i = 0; i < 4; i++) {
            int idx = tid * 4 + i;              // hh*64 + r
            int hh = idx >> 6, r = idx & 63;
            size_t li = (size_t)(bb * 16 + hh) * 2048 + t0 + r;
            float l = lp[li] + lp[65536 + li];
            lh[hh][r] = (f16)(1.0f / l);
        }
    }

    f32x4 acc[2][2];
#pragma unroll
    for (int i = 0; i < 2; i++)
#pragma unroll
        for (int j = 0; j < 2; j++) acc[i][j] = (f32x4){0.f, 0.f, 0.f, 0.f};

    for (int k0 = 0; k0 < 1024; k0 += 64) {
        __syncthreads();
#pragma unroll
        for (int j = 0; j < 2; j++) {
            const int inst = wid * 2 + j;
            const int r = inst * 8 + sr;
            ASYNC16(Ab0 + (size_t)r * 1024 + k0 + sc, &As0[inst * 512]);
            ASYNC16(Ab1 + (size_t)r * 1024 + k0 + sc, &As1[inst * 512]);
            ASYNC16(Bb + (size_t)r * 1024 + k0 + sc, &Bs[inst * 512]);
        }
        __syncthreads();
        const int hd = k0 >> 6;
        f16 scl[2];
#pragma unroll
        for (int mb = 0; mb < 2; mb++) scl[mb] = lh[hd][row0 + mb * 16 + ml];
#pragma unroll
        for (int kh = 0; kh < 2; kh++) {
            f16x8 af[2], bf[2];
#pragma unroll
            for (int mb = 0; mb < 2; mb++) {
                const int off = (row0 + mb * 16 + ml) * 64 + ((kh * 4 + qq) ^ swz) * 8;
                f16x8 a0 = *(const f16x8*)(&As0[off]);
                f16x8 a1 = *(const f16x8*)(&As1[off]);
                f16x8 sum = a0 + a1;
                f16x8 av;
#pragma unroll
                for (int e = 0; e < 8; e++) av[e] = sum[e] * scl[mb];
                af[mb] = av;
            }
#pragma unroll
            for (int nb = 0; nb < 2; nb++)
                bf[nb] = *(const f16x8*)(&Bs[(col0 + nb * 16 + ml) * 64 + ((kh * 4 + qq) ^ swz) * 8]);
#pragma unroll
            for (int mb = 0; mb < 2; mb++)
#pragma unroll
                for (int nb = 0; nb < 2; nb++)
                    acc[mb][nb] = MFMA_F16(af[mb], bf[nb], acc[mb][nb]);
        }
    }

    const int rT = r0g + row0 + qq * 4;
#pragma unroll
    for (int mb = 0; mb < 2; mb++)
#pragma unroll
        for (int nb = 0; nb < 2; nb++) {
            int c = blockIdx.y * 64 + col0 + nb * 16 + ml;
            float bv = bias[c];
#pragma unroll
            for (int rg = 0; rg < 4; rg++)
                C[(size_t)(rT + mb * 16 + rg) * 1024 + c] = acc[mb][nb][rg] + bv;
        }
}

// ---------------------------------------------------------------------------
extern "C" void kernel_launch(void* const* d_in, const int* in_sizes, int n_in,
                              void* d_out, int out_size, void* d_ws, size_t ws_size,
                              hipStream_t stream)
{
    const float* x     = (const float*)d_in[0];
    const float* gamma = (const float*)d_in[1];
    const float* beta  = (const float*)d_in[2];
    const float* wq    = (const float*)d_in[3];
    const float* wk    = (const float*)d_in[4];
    const float* wv    = (const float*)d_in[5];
    const float* wo    = (const float*)d_in[6];
    const float* wout  = (const float*)d_in[7];
    const float* bout  = (const float*)d_in[8];
    float* out = (float*)d_out;

    char* ws = (char*)d_ws;
    const size_t MB = 1 << 20;
    f16* xn    = (f16*)(ws + 0);        // 8 MB [4096][1024]; reused as Op0 after QKV
    f16* wqt   = (f16*)(ws + 8 * MB);   // wqt/wkt/wvt contiguous = [3072][1024]
    f16* wkt   = (f16*)(ws + 10 * MB);
    f16* wvt   = (f16*)(ws + 12 * MB);
    f16* wo_h  = (f16*)(ws + 14 * MB);
    f16* woutt = (f16*)(ws + 16 * MB);
    f16* W2t   = (f16*)(ws + 18 * MB);  // (wo @ w_out)^T fp16
    f16* Qh    = (f16*)(ws + 20 * MB);  // 8 MB [32][2048][64]
    f16* Kh    = (f16*)(ws + 28 * MB);  // 8 MB [32][2048][64]
    f16* Vth   = (f16*)(ws + 36 * MB);  // 8 MB [32][64][2048]
    f16* Op0   = xn;                    // alias: xn dead after QKV GEMM
    f16* Op1   = (f16*)(ws + 8 * MB);   // alias: wqt..wo_h dead after QKV GEMM
    float* lp  = (float*)(ws + 16 * MB);// alias: woutt dead after QKV (512 KB)

    pre_kernel<<<5376, 256, 0, stream>>>(x, gamma, beta, xn, wq, wk, wv, wo, wout,
                                         wqt, wkt, wvt, wo_h, woutt);
    // fused QKV (A[4096,1024] x Wqkv_t[3072,1024]^T) + W2t (64 tail blocks)
    gemm_qkv_w2<<<dim3(32, 26), 256, 0, stream>>>(xn, wqt, Qh, Kh, Vth,
                                                  woutt, wo_h, W2t);
    flash_kernel<<<dim3(16, 32, 2), 256, 0, stream>>>(Qh, Kh, Vth, Op0, Op1, lp);
    gemm_final<<<dim3(64, 16), 256, 0, stream>>>(Op0, Op1, W2t, lp, out, bout);
}